// Round 5
// baseline (651.080 us; speedup 1.0000x reference)
//
#include <hip/hip_runtime.h>
#include <cstdint>
#include <cstddef>

typedef __bf16 bf16;
typedef bf16 bf16x2 __attribute__((ext_vector_type(2)));
typedef bf16 bf16x4 __attribute__((ext_vector_type(4)));
typedef bf16 bf16x8 __attribute__((ext_vector_type(8)));
typedef float f32x4 __attribute__((ext_vector_type(4)));

// Stored-channel permutation (within each 64-channel block):
//   stored s  <->  source (s&~63) | ((s&3)<<4) | ((s&63)>>2)
// t1/t2 live in stored order; w2t/wlt/bnfinal absorb the mapping.
__device__ __forceinline__ int perm_src(int s) {
  return (s & ~63) | ((s & 3) << 4) | ((s & 63) >> 2);
}

// ---------------- graph preprocessing ----------------
__global__ void k_init(int* __restrict__ deg, int* __restrict__ cur,
                       float* __restrict__ sums1, float* __restrict__ sums2, int N) {
  int i = blockIdx.x * 256 + threadIdx.x;
  if (i < N) { deg[i] = 1; cur[i] = 0; }   // deg starts at 1: self loop
  if (i < 512)  sums1[i] = 0.f;
  if (i < 1024) sums2[i] = 0.f;
}

__global__ void k_count(const int* __restrict__ ei, int* __restrict__ deg, int E) {
  int e = blockIdx.x * 256 + threadIdx.x;
  if (e < E) atomicAdd(&deg[ei[E + e]], 1);   // dst = ei[E+e]
}

// hierarchical scan of (deg-1): scan1 block sums -> scan2 scans sums -> scan3 writes roff
__global__ __launch_bounds__(256) void k_scan1(const int* __restrict__ deg,
                                               int* __restrict__ bsum, int N) {
  int t = threadIdx.x;
  int i = blockIdx.x * 256 + t;
  int v = (i < N) ? deg[i] - 1 : 0;
#pragma unroll
  for (int off = 32; off > 0; off >>= 1) v += __shfl_down(v, off, 64);
  __shared__ int red[4];
  if ((t & 63) == 0) red[t >> 6] = v;
  __syncthreads();
  if (t == 0) bsum[blockIdx.x] = red[0] + red[1] + red[2] + red[3];
}

__global__ __launch_bounds__(256) void k_scan2(const int* __restrict__ bsum,
                                               int* __restrict__ bpre, int B) {
  __shared__ int s[256];
  int t = threadIdx.x;
  int v = (t < B) ? bsum[t] : 0;
  s[t] = v;
  __syncthreads();
  for (int off = 1; off < 256; off <<= 1) {
    int add = (t >= off) ? s[t - off] : 0;
    __syncthreads();
    s[t] += add;
    __syncthreads();
  }
  if (t < B) bpre[t] = s[t] - v;   // exclusive
}

__global__ __launch_bounds__(256) void k_scan3(const int* __restrict__ deg,
                                               const int* __restrict__ bpre,
                                               int* __restrict__ roff,
                                               float* __restrict__ dinv, int N) {
  __shared__ int s[256];
  int t = threadIdx.x;
  int i = blockIdx.x * 256 + t;
  int d = (i < N) ? deg[i] : 1;
  int v = d - 1;
  if (i >= N) v = 0;
  s[t] = v;
  __syncthreads();
  for (int off = 1; off < 256; off <<= 1) {
    int add = (t >= off) ? s[t - off] : 0;
    __syncthreads();
    s[t] += add;
    __syncthreads();
  }
  if (i < N) {
    int base = bpre[blockIdx.x];
    roff[i] = base + s[t] - v;
    dinv[i] = rsqrtf((float)d);
    if (i == N - 1) roff[N] = base + s[t];
  }
}

__global__ void k_scatter(const int* __restrict__ ei, const int* __restrict__ roff,
                          int* __restrict__ cur, int* __restrict__ csr, int E) {
  int e = blockIdx.x * 256 + threadIdx.x;
  if (e >= E) return;
  int d = ei[E + e];
  int p = atomicAdd(&cur[d], 1);
  csr[roff[d] + p] = ei[e];   // src
}

// ---------------- dtype conversion ----------------
__global__ void k_cvt_x(const float* __restrict__ x, bf16* __restrict__ xb, size_t total) {
  size_t base = ((size_t)blockIdx.x * 256 + threadIdx.x) * 4;
  if (base >= total) return;
  const float4 v = *(const float4*)(x + base);
  bf16x4 o;
  o[0] = (bf16)v.x; o[1] = (bf16)v.y; o[2] = (bf16)v.z; o[3] = (bf16)v.w;
  *(bf16x4*)(xb + base) = o;
}

// merged transpose+cast of all three weights: Wt[n][k] = W[src_k][n]
// w1t natural (x channels unpermuted); w2t/wlt k-index permuted to match the
// stored layout of t1/t2.
__global__ void k_cvt_w(const float* __restrict__ W1, const float* __restrict__ W2,
                        const float* __restrict__ Wl, bf16* __restrict__ w1t,
                        bf16* __restrict__ w2t, bf16* __restrict__ wlt) {
  int i = blockIdx.x * 256 + threadIdx.x;   // grid covers 229376 exactly
  if (i < 32768) {
    int n = i >> 7, k = i & 127;
    w1t[i] = (bf16)W1[(size_t)k * 256 + n];
  } else if (i < 163840) {
    int j = i - 32768;
    int n = j >> 8, ks = j & 255;
    w2t[j] = (bf16)W2[(size_t)perm_src(ks) * 512 + n];
  } else {
    int j = i - 163840;
    int n = j >> 9, ks = j & 511;
    wlt[j] = (bf16)Wl[(size_t)perm_src(ks) * 128 + n];
  }
}

// ---------------- bf16 MFMA GEMM: C[M,NOUT] = A[M,K] @ Bt[NOUT,K]^T ----------------
// ALL-REGISTER variant: no LDS, no barriers. Each lane loads its MFMA A/B
// fragments (bf16x8 = 16B) directly from global. Per wave-instruction the
// (q,mr) lane layout covers a 16-row x 64B rectangle = 16 cache lines (the
// minimum), vs 64 lines for the old lane->row staging. The fully unrolled
// K-loop lets the compiler pipeline chunk k+1 loads under chunk k MFMAs;
// waves never lockstep on barriers. A/B overlap between waves hits L1.
// Non-FINAL epilogue: packed bf16x4 stores in STORED channel order
// (stored = cw + mr*4 + c  <->  source col = cw + c*16 + mr) + fused BN stats.
// FINAL: natural-layout fp32 stores, masked to real rows.
template<int K, int NOUT, bool FINAL>
__global__ __launch_bounds__(256) void k_gemm(const bf16* __restrict__ A,
                                              const bf16* __restrict__ Bt,
                                              bf16* __restrict__ outB,
                                              float* __restrict__ outF,
                                              const float* __restrict__ bias,
                                              float* __restrict__ sums,
                                              int Mreal) {
  const int tid = threadIdx.x;
  const int wv = tid >> 6, lane = tid & 63;
  const int q = lane >> 4, mr = lane & 15;
  const int m0 = blockIdx.x * 128;   // m fastest (R3 orientation)
  const int n0 = blockIdx.y * 128;
  const int rw = (wv >> 1) * 64, cw = (wv & 1) * 64;

  // fragment base pointers: row = m0+rw+r*16+mr (A) / n0+cw+c*16+mr (B), k = k0+q*8
  const bf16* Ab = A + (size_t)(m0 + rw + mr) * K + q * 8;
  const bf16* Bb = Bt + (size_t)(n0 + cw + mr) * K + q * 8;

  f32x4 acc[4][4];
#pragma unroll
  for (int r = 0; r < 4; ++r)
#pragma unroll
    for (int c = 0; c < 4; ++c) acc[r][c] = (f32x4){0.f, 0.f, 0.f, 0.f};

#pragma unroll
  for (int k0 = 0; k0 < K; k0 += 32) {
    bf16x8 af[4], bfr[4];
#pragma unroll
    for (int r = 0; r < 4; ++r)
      af[r] = *(const bf16x8*)(Ab + (size_t)(r * 16) * K + k0);
#pragma unroll
    for (int c = 0; c < 4; ++c)
      bfr[c] = *(const bf16x8*)(Bb + (size_t)(c * 16) * K + k0);
#pragma unroll
    for (int r = 0; r < 4; ++r)
#pragma unroll
      for (int c = 0; c < 4; ++c)
        acc[r][c] = __builtin_amdgcn_mfma_f32_16x16x32_bf16(af[r], bfr[c], acc[r][c], 0, 0, 0);
  }

  // C/D layout: source col = lane&15 (+c*16), row = (lane>>4)*4 + reg
  if (FINAL) {
#pragma unroll
    for (int c = 0; c < 4; ++c) {
      const int col = n0 + cw + c * 16 + mr;
#pragma unroll
      for (int r = 0; r < 4; ++r) {
#pragma unroll
        for (int i = 0; i < 4; ++i) {
          int row = m0 + rw + r * 16 + q * 4 + i;
          if (row < Mreal) outF[(size_t)row * NOUT + col] = acc[r][c][i] + bias[col];
        }
      }
    }
  } else {
    // packed stored-order bf16x4 stores: 128B contiguous per 16-lane group
#pragma unroll
    for (int r = 0; r < 4; ++r) {
#pragma unroll
      for (int i = 0; i < 4; ++i) {
        int row = m0 + rw + r * 16 + q * 4 + i;
        bf16x4 pk;
        pk[0] = (bf16)acc[r][0][i]; pk[1] = (bf16)acc[r][1][i];
        pk[2] = (bf16)acc[r][2][i]; pk[3] = (bf16)acc[r][3][i];
        *(bf16x4*)(outB + (size_t)row * NOUT + n0 + cw + mr * 4) = pk;
      }
    }
    // BN stats at stored channel = n0 + cw + mr*4 + c
#pragma unroll
    for (int c = 0; c < 4; ++c) {
      float s0 = 0.f, s1 = 0.f;
#pragma unroll
      for (int r = 0; r < 4; ++r) {
#pragma unroll
        for (int i = 0; i < 4; ++i) {
          int row = m0 + rw + r * 16 + q * 4 + i;
          float v = acc[r][c][i];
          if (row < Mreal) { s0 += v; s1 += v * v; }
        }
      }
      s0 += __shfl_xor(s0, 16, 64); s0 += __shfl_xor(s0, 32, 64);
      s1 += __shfl_xor(s1, 16, 64); s1 += __shfl_xor(s1, 32, 64);
      if (q == 0) {
        int sch = n0 + cw + mr * 4 + c;
        atomicAdd(&sums[sch], s0); atomicAdd(&sums[NOUT + sch], s1);
      }
    }
  }
}

// ---------------- CSR aggregation (one wave per node) ----------------
// g[v] = dinv[v] * ( sum_e dinv[s]*f(h[s]) + dinv[v]*f(h[v]) )
// f = identity or fused BN+ReLU of prev layer (per-stored-channel scale/shift).
template<int C, bool BN>
__global__ __launch_bounds__(256) void k_agg(const bf16* __restrict__ h,
                                             bf16* __restrict__ g,
                                             const int* __restrict__ csr,
                                             const int* __restrict__ roff,
                                             const float* __restrict__ dinv,
                                             const float* __restrict__ scale,
                                             const float* __restrict__ shift,
                                             int N) {
  constexpr int VPL = C / 64;   // channels per lane: 2 or 4
  const int lane = threadIdx.x & 63;
  const int v = (int)(((unsigned)blockIdx.x * 256 + threadIdx.x) >> 6);
  if (v >= N) return;
  float sc[VPL], sh[VPL];
  if constexpr (BN) {
#pragma unroll
    for (int u = 0; u < VPL; ++u) { sc[u] = scale[lane * VPL + u]; sh[u] = shift[lane * VPL + u]; }
  }
  const float dv = dinv[v];
  float acc[VPL];
#pragma unroll
  for (int u = 0; u < VPL; ++u) acc[u] = 0.f;

  auto accum = [&](int src, float w) {
    const bf16* hr = h + (size_t)src * C + lane * VPL;
    float vals[VPL];
    if constexpr (VPL == 2) {
      bf16x2 t = *(const bf16x2*)hr;
      vals[0] = (float)t[0]; vals[1] = (float)t[1];
    } else {
      bf16x4 t = *(const bf16x4*)hr;
#pragma unroll
      for (int u = 0; u < 4; ++u) vals[u] = (float)t[u];
    }
#pragma unroll
    for (int u = 0; u < VPL; ++u) {
      float xx = vals[u];
      if constexpr (BN) xx = fmaxf(0.f, xx * sc[u] + sh[u]);
      acc[u] += w * xx;
    }
  };

  accum(v, dv);   // self loop (becomes dv^2 after final *dv)
  const int beg = roff[v], end = roff[v + 1];
  for (int base = beg; base < end; base += 64) {
    int cnt = min(64, end - base);
    int s = 0; float w = 0.f;
    if (lane < cnt) { s = csr[base + lane]; w = dinv[s]; }
    for (int j = 0; j < cnt; ++j) {
      int sj = __shfl(s, j, 64);
      float wj = __shfl(w, j, 64);
      accum(sj, wj);
    }
  }

  bf16* gv = g + (size_t)v * C + lane * VPL;
  if constexpr (VPL == 2) {
    bf16x2 o;
    o[0] = (bf16)(acc[0] * dv); o[1] = (bf16)(acc[1] * dv);
    *(bf16x2*)gv = o;
  } else {
    bf16x4 o;
#pragma unroll
    for (int u = 0; u < 4; ++u) o[u] = (bf16)(acc[u] * dv);
    *(bf16x4*)gv = o;
  }
}

// ---------------- BatchNorm ----------------
// sums/scale/shift are in STORED channel order; gamma/beta are source-order.
__global__ void k_bnfinal(const float* __restrict__ sums, const float* __restrict__ gamma,
                          const float* __restrict__ beta, float* __restrict__ scale,
                          float* __restrict__ shift, int C, float invN) {
  int c = blockIdx.x * 256 + threadIdx.x;
  if (c >= C) return;
  int src = perm_src(c);
  float mu = sums[c] * invN;
  float var = sums[C + c] * invN - mu * mu;   // biased var (ddof=0)
  float is = rsqrtf(var + 1e-5f);
  float sc = gamma[src] * is;
  scale[c] = sc;
  shift[c] = beta[src] - mu * sc;
}

// in-place BN+ReLU, 8-wide (pad rows processed too: finite garbage, masked downstream)
template<int C>
__global__ void k_bnapply(bf16* __restrict__ g, const float* __restrict__ scale,
                          const float* __restrict__ shift, size_t total) {
  size_t base = ((size_t)blockIdx.x * 256 + threadIdx.x) * 8;
  if (base >= total) return;
  int col = (int)(base & (size_t)(C - 1));
  bf16x8 t = *(const bf16x8*)(g + base);
  bf16x8 o;
#pragma unroll
  for (int j = 0; j < 8; ++j)
    o[j] = (bf16)fmaxf(0.f, (float)t[j] * scale[col + j] + shift[col + j]);
  *(bf16x8*)(g + base) = o;
}

// ---------------- launch ----------------
extern "C" void kernel_launch(void* const* d_in, const int* in_sizes, int n_in,
                              void* d_out, int out_size, void* d_ws, size_t ws_size,
                              hipStream_t stream) {
  const float* x   = (const float*)d_in[0];
  const int*   ei  = (const int*)d_in[1];
  const float* W1  = (const float*)d_in[2];
  // d_in[3] = b1: absorbed by BN (mean subtraction cancels it)
  const float* g1  = (const float*)d_in[4];
  const float* be1 = (const float*)d_in[5];
  const float* W2  = (const float*)d_in[6];
  // d_in[7] = b2: absorbed by BN
  const float* g2  = (const float*)d_in[8];
  const float* be2 = (const float*)d_in[9];
  const float* Wl  = (const float*)d_in[10];
  const float* bl  = (const float*)d_in[11];
  float* out = (float*)d_out;

  const int N  = in_sizes[0] / 128;          // 50000
  const int E  = in_sizes[1] / 2;            // 500000
  const int Mp = ((N + 127) / 128) * 128;    // 50048 = 391*128
  const int NB = (N + 255) / 256;            // scan blocks (196)

  char* p = (char*)d_ws;
  auto carve = [&](size_t bytes) { void* r = (void*)p; p += (bytes + 255) & ~(size_t)255; return r; };
  int*   deg   = (int*)carve(sizeof(int) * N);
  int*   cur   = (int*)carve(sizeof(int) * N);
  int*   roff  = (int*)carve(sizeof(int) * (N + 1));
  int*   csr   = (int*)carve(sizeof(int) * E);
  int*   bsum  = (int*)carve(sizeof(int) * 256);
  int*   bpre  = (int*)carve(sizeof(int) * 256);
  float* dinv  = (float*)carve(sizeof(float) * N);
  float* sums1 = (float*)carve(sizeof(float) * 512);
  float* sums2 = (float*)carve(sizeof(float) * 1024);
  float* sc1   = (float*)carve(sizeof(float) * 256);
  float* sh1   = (float*)carve(sizeof(float) * 256);
  float* sc2   = (float*)carve(sizeof(float) * 512);
  float* sh2   = (float*)carve(sizeof(float) * 512);
  bf16*  w1t   = (bf16*)carve(sizeof(bf16) * 256 * 128);
  bf16*  w2t   = (bf16*)carve(sizeof(bf16) * 512 * 256);
  bf16*  wlt   = (bf16*)carve(sizeof(bf16) * 128 * 512);
  bf16*  xb    = (bf16*)carve(sizeof(bf16) * (size_t)Mp * 128);
  bf16*  ax1   = (bf16*)carve(sizeof(bf16) * (size_t)Mp * 128);  // agg(x)
  bf16*  t1    = (bf16*)carve(sizeof(bf16) * (size_t)Mp * 256);  // ax1 @ W1 (stored order)
  bf16*  ax2   = (bf16*)carve(sizeof(bf16) * (size_t)Mp * 256);  // agg(relu(bn(t1)))
  bf16*  t2    = (bf16*)carve(sizeof(bf16) * (size_t)Mp * 512);  // ax2 @ W2 (stored order)
  (void)n_in; (void)out_size; (void)ws_size;

  const int gE = (E + 255) / 256;
  k_init<<<NB, 256, 0, stream>>>(deg, cur, sums1, sums2, N);
  k_count<<<gE, 256, 0, stream>>>(ei, deg, E);
  k_scan1<<<NB, 256, 0, stream>>>(deg, bsum, N);
  k_scan2<<<1, 256, 0, stream>>>(bsum, bpre, NB);
  k_scan3<<<NB, 256, 0, stream>>>(deg, bpre, roff, dinv, N);   // dinv fused
  k_scatter<<<gE, 256, 0, stream>>>(ei, roff, cur, csr, E);

  k_cvt_x<<<(int)(((size_t)N * 128 / 4 + 255) / 256), 256, 0, stream>>>(x, xb, (size_t)N * 128);
  k_cvt_w<<<896, 256, 0, stream>>>(W1, W2, Wl, w1t, w2t, wlt);

  const int gAgg = (N + 3) / 4;
  // layer 1: aggregate first (S commutes with dense transform), then GEMM(+stats)
  k_agg<128, false><<<gAgg, 256, 0, stream>>>(xb, ax1, csr, roff, dinv, nullptr, nullptr, N);
  k_gemm<128, 256, false><<<dim3(Mp / 128, 2), 256, 0, stream>>>(ax1, w1t, t1, nullptr, nullptr, sums1, N);
  k_bnfinal<<<1, 256, 0, stream>>>(sums1, g1, be1, sc1, sh1, 256, 1.f / (float)N);

  // layer 2: gather applies BN1+ReLU on the fly (stored-channel order throughout)
  k_agg<256, true><<<gAgg, 256, 0, stream>>>(t1, ax2, csr, roff, dinv, sc1, sh1, N);
  k_gemm<256, 512, false><<<dim3(Mp / 128, 4), 256, 0, stream>>>(ax2, w2t, t2, nullptr, nullptr, sums2, N);
  k_bnfinal<<<2, 256, 0, stream>>>(sums2, g2, be2, sc2, sh2, 512, 1.f / (float)N);
  k_bnapply<512><<<(int)(((size_t)Mp * 512 / 8 + 255) / 256), 256, 0, stream>>>(t2, sc2, sh2, (size_t)Mp * 512);

  // final linear: out = a2 @ Wl + bl (fp32 natural-layout store, masked to real rows)
  k_gemm<512, 128, true><<<dim3(Mp / 128, 1), 256, 0, stream>>>(t2, wlt, nullptr, out, bl, nullptr, N);
}

// Round 6
// 604.099 us; speedup vs baseline: 1.0778x; 1.0778x over previous
//
#include <hip/hip_runtime.h>
#include <cstdint>
#include <cstddef>

typedef __bf16 bf16;
typedef bf16 bf16x2 __attribute__((ext_vector_type(2)));
typedef bf16 bf16x4 __attribute__((ext_vector_type(4)));
typedef bf16 bf16x8 __attribute__((ext_vector_type(8)));
typedef float f32x4 __attribute__((ext_vector_type(4)));

// Stored-channel permutation (within each 64-channel block):
//   stored s  <->  source (s&~63) | ((s&3)<<4) | ((s&63)>>2)
// t1/t2 live in stored order; w2t/wlt/bnfinal absorb the mapping.
__device__ __forceinline__ int perm_src(int s) {
  return (s & ~63) | ((s & 3) << 4) | ((s & 63) >> 2);
}

// ---------------- graph preprocessing ----------------
__global__ void k_init(int* __restrict__ deg, int* __restrict__ cur,
                       float* __restrict__ sums1, float* __restrict__ sums2, int N) {
  int i = blockIdx.x * 256 + threadIdx.x;
  if (i < N) { deg[i] = 1; cur[i] = 0; }   // deg starts at 1: self loop
  if (i < 512)  sums1[i] = 0.f;
  if (i < 1024) sums2[i] = 0.f;
}

__global__ void k_count(const int* __restrict__ ei, int* __restrict__ deg, int E) {
  int e = blockIdx.x * 256 + threadIdx.x;
  if (e < E) atomicAdd(&deg[ei[E + e]], 1);   // dst = ei[E+e]
}

// hierarchical scan of (deg-1): scan1 block sums -> scan2 scans sums -> scan3 writes roff
__global__ __launch_bounds__(256) void k_scan1(const int* __restrict__ deg,
                                               int* __restrict__ bsum, int N) {
  int t = threadIdx.x;
  int i = blockIdx.x * 256 + t;
  int v = (i < N) ? deg[i] - 1 : 0;
#pragma unroll
  for (int off = 32; off > 0; off >>= 1) v += __shfl_down(v, off, 64);
  __shared__ int red[4];
  if ((t & 63) == 0) red[t >> 6] = v;
  __syncthreads();
  if (t == 0) bsum[blockIdx.x] = red[0] + red[1] + red[2] + red[3];
}

__global__ __launch_bounds__(256) void k_scan2(const int* __restrict__ bsum,
                                               int* __restrict__ bpre, int B) {
  __shared__ int s[256];
  int t = threadIdx.x;
  int v = (t < B) ? bsum[t] : 0;
  s[t] = v;
  __syncthreads();
  for (int off = 1; off < 256; off <<= 1) {
    int add = (t >= off) ? s[t - off] : 0;
    __syncthreads();
    s[t] += add;
    __syncthreads();
  }
  if (t < B) bpre[t] = s[t] - v;   // exclusive
}

__global__ __launch_bounds__(256) void k_scan3(const int* __restrict__ deg,
                                               const int* __restrict__ bpre,
                                               int* __restrict__ roff,
                                               float* __restrict__ dinv, int N) {
  __shared__ int s[256];
  int t = threadIdx.x;
  int i = blockIdx.x * 256 + t;
  int d = (i < N) ? deg[i] : 1;
  int v = d - 1;
  if (i >= N) v = 0;
  s[t] = v;
  __syncthreads();
  for (int off = 1; off < 256; off <<= 1) {
    int add = (t >= off) ? s[t - off] : 0;
    __syncthreads();
    s[t] += add;
    __syncthreads();
  }
  if (i < N) {
    int base = bpre[blockIdx.x];
    roff[i] = base + s[t] - v;
    dinv[i] = rsqrtf((float)d);
    if (i == N - 1) roff[N] = base + s[t];
  }
}

__global__ void k_scatter(const int* __restrict__ ei, const int* __restrict__ roff,
                          int* __restrict__ cur, int* __restrict__ csr, int E) {
  int e = blockIdx.x * 256 + threadIdx.x;
  if (e >= E) return;
  int d = ei[E + e];
  int p = atomicAdd(&cur[d], 1);
  csr[roff[d] + p] = ei[e];   // src
}

// ---------------- dtype conversion ----------------
__global__ void k_cvt_x(const float* __restrict__ x, bf16* __restrict__ xb, size_t total) {
  size_t base = ((size_t)blockIdx.x * 256 + threadIdx.x) * 4;
  if (base >= total) return;
  const float4 v = *(const float4*)(x + base);
  bf16x4 o;
  o[0] = (bf16)v.x; o[1] = (bf16)v.y; o[2] = (bf16)v.z; o[3] = (bf16)v.w;
  *(bf16x4*)(xb + base) = o;
}

// merged transpose+cast of all three weights: Wt[n][k] = W[src_k][n]
// w1t natural (x channels unpermuted); w2t/wlt k-index permuted to match the
// stored layout of t1/t2.
__global__ void k_cvt_w(const float* __restrict__ W1, const float* __restrict__ W2,
                        const float* __restrict__ Wl, bf16* __restrict__ w1t,
                        bf16* __restrict__ w2t, bf16* __restrict__ wlt) {
  int i = blockIdx.x * 256 + threadIdx.x;   // grid covers 229376 exactly
  if (i < 32768) {
    int n = i >> 7, k = i & 127;
    w1t[i] = (bf16)W1[(size_t)k * 256 + n];
  } else if (i < 163840) {
    int j = i - 32768;
    int n = j >> 8, ks = j & 255;
    w2t[j] = (bf16)W2[(size_t)perm_src(ks) * 512 + n];
  } else {
    int j = i - 163840;
    int n = j >> 9, ks = j & 511;
    wlt[j] = (bf16)Wl[(size_t)perm_src(ks) * 128 + n];
  }
}

// ---------------- bf16 MFMA GEMM: C[M,NOUT] = A[M,K] @ Bt[NOUT,K]^T ----------------
// 128x128 tile, BK=32, LDS-staged via global_load_lds width=16.
// STAGING SWIZZLE (the R6 change): LDS slot s holds (row = s>>2,
// kc = (s&3) ^ ((s>>4)&3)), so 4 consecutive lanes fetch one contiguous 64B
// line of one row -> 16 global lines per staging instruction (was 64 with
// the [kb][row] layout: each lane its own row at 512B stride).
// Fragment read: slot = row*4 + (q ^ ((mr>>2)&3)); bank footprint
// 4*(mr&1) + q^(mr>>2) mod 8 -> 8 groups x 2 lanes = 2-way conflict = free.
// Non-FINAL epilogue: packed bf16x4 stores in STORED channel order
// (stored = cw + mr*4 + c <-> source col = cw + c*16 + mr) + fused BN stats.
// FINAL: natural-layout fp32 stores, masked to real rows.
template<int K, int NOUT, bool FINAL>
__global__ __launch_bounds__(256) void k_gemm(const bf16* __restrict__ A,
                                              const bf16* __restrict__ Bt,
                                              bf16* __restrict__ outB,
                                              float* __restrict__ outF,
                                              const float* __restrict__ bias,
                                              float* __restrict__ sums,
                                              int Mreal) {
  __shared__ uint4 lA[512];
  __shared__ uint4 lB[512];
  const int tid = threadIdx.x;
  const int wv = tid >> 6, lane = tid & 63;
  const int q = lane >> 4, mr = lane & 15;
  const int m0 = blockIdx.x * 128;   // m fastest (R3 orientation: B fully L2-resident)
  const int n0 = blockIdx.y * 128;
  const int rw = (wv >> 1) * 64, cw = (wv & 1) * 64;
  const int cxor = (mr >> 2) & 3;    // read-side XOR key

  f32x4 acc[4][4];
#pragma unroll
  for (int r = 0; r < 4; ++r)
#pragma unroll
    for (int c = 0; c < 4; ++c) acc[r][c] = (f32x4){0.f, 0.f, 0.f, 0.f};

  for (int k0 = 0; k0 < K; k0 += 32) {
    __syncthreads();
#pragma unroll
    for (int it = 0; it < 2; ++it) {
      int s = it * 256 + tid;
      int row = s >> 2;
      int kc = (s & 3) ^ ((s >> 4) & 3);
      const bf16* ga = A + (size_t)(m0 + row) * K + (k0 + kc * 8);
      const bf16* gb = Bt + (size_t)(n0 + row) * K + (k0 + kc * 8);
      __builtin_amdgcn_global_load_lds((const __attribute__((address_space(1))) void*)ga,
                                       (__attribute__((address_space(3))) void*)(lA + s), 16, 0, 0);
      __builtin_amdgcn_global_load_lds((const __attribute__((address_space(1))) void*)gb,
                                       (__attribute__((address_space(3))) void*)(lB + s), 16, 0, 0);
    }
    __syncthreads();
    bf16x8 af[4], bfr[4];
#pragma unroll
    for (int r = 0; r < 4; ++r)
      af[r] = ((const bf16x8*)lA)[(rw + r * 16 + mr) * 4 + (q ^ cxor)];
#pragma unroll
    for (int c = 0; c < 4; ++c)
      bfr[c] = ((const bf16x8*)lB)[(cw + c * 16 + mr) * 4 + (q ^ cxor)];
#pragma unroll
    for (int r = 0; r < 4; ++r)
#pragma unroll
      for (int c = 0; c < 4; ++c)
        acc[r][c] = __builtin_amdgcn_mfma_f32_16x16x32_bf16(af[r], bfr[c], acc[r][c], 0, 0, 0);
  }

  // C/D layout: source col = lane&15 (+c*16), row = (lane>>4)*4 + reg
  if (FINAL) {
#pragma unroll
    for (int c = 0; c < 4; ++c) {
      const int col = n0 + cw + c * 16 + mr;
#pragma unroll
      for (int r = 0; r < 4; ++r) {
#pragma unroll
        for (int i = 0; i < 4; ++i) {
          int row = m0 + rw + r * 16 + q * 4 + i;
          if (row < Mreal) outF[(size_t)row * NOUT + col] = acc[r][c][i] + bias[col];
        }
      }
    }
  } else {
    // packed stored-order bf16x4 stores: 128B contiguous per 16-lane group
#pragma unroll
    for (int r = 0; r < 4; ++r) {
#pragma unroll
      for (int i = 0; i < 4; ++i) {
        int row = m0 + rw + r * 16 + q * 4 + i;
        bf16x4 pk;
        pk[0] = (bf16)acc[r][0][i]; pk[1] = (bf16)acc[r][1][i];
        pk[2] = (bf16)acc[r][2][i]; pk[3] = (bf16)acc[r][3][i];
        *(bf16x4*)(outB + (size_t)row * NOUT + n0 + cw + mr * 4) = pk;
      }
    }
    // BN stats at stored channel = n0 + cw + mr*4 + c
#pragma unroll
    for (int c = 0; c < 4; ++c) {
      float s0 = 0.f, s1 = 0.f;
#pragma unroll
      for (int r = 0; r < 4; ++r) {
#pragma unroll
        for (int i = 0; i < 4; ++i) {
          int row = m0 + rw + r * 16 + q * 4 + i;
          float v = acc[r][c][i];
          if (row < Mreal) { s0 += v; s1 += v * v; }
        }
      }
      s0 += __shfl_xor(s0, 16, 64); s0 += __shfl_xor(s0, 32, 64);
      s1 += __shfl_xor(s1, 16, 64); s1 += __shfl_xor(s1, 32, 64);
      if (q == 0) {
        int sch = n0 + cw + mr * 4 + c;
        atomicAdd(&sums[sch], s0); atomicAdd(&sums[NOUT + sch], s1);
      }
    }
  }
}

// ---------------- CSR aggregation (one wave per node) ----------------
// g[v] = dinv[v] * ( sum_e dinv[s]*f(h[s]) + dinv[v]*f(h[v]) )
// f = identity or fused BN+ReLU of prev layer (per-stored-channel scale/shift).
template<int C, bool BN>
__global__ __launch_bounds__(256) void k_agg(const bf16* __restrict__ h,
                                             bf16* __restrict__ g,
                                             const int* __restrict__ csr,
                                             const int* __restrict__ roff,
                                             const float* __restrict__ dinv,
                                             const float* __restrict__ scale,
                                             const float* __restrict__ shift,
                                             int N) {
  constexpr int VPL = C / 64;   // channels per lane: 2 or 4
  const int lane = threadIdx.x & 63;
  const int v = (int)(((unsigned)blockIdx.x * 256 + threadIdx.x) >> 6);
  if (v >= N) return;
  float sc[VPL], sh[VPL];
  if constexpr (BN) {
#pragma unroll
    for (int u = 0; u < VPL; ++u) { sc[u] = scale[lane * VPL + u]; sh[u] = shift[lane * VPL + u]; }
  }
  const float dv = dinv[v];
  float acc[VPL];
#pragma unroll
  for (int u = 0; u < VPL; ++u) acc[u] = 0.f;

  auto accum = [&](int src, float w) {
    const bf16* hr = h + (size_t)src * C + lane * VPL;
    float vals[VPL];
    if constexpr (VPL == 2) {
      bf16x2 t = *(const bf16x2*)hr;
      vals[0] = (float)t[0]; vals[1] = (float)t[1];
    } else {
      bf16x4 t = *(const bf16x4*)hr;
#pragma unroll
      for (int u = 0; u < 4; ++u) vals[u] = (float)t[u];
    }
#pragma unroll
    for (int u = 0; u < VPL; ++u) {
      float xx = vals[u];
      if constexpr (BN) xx = fmaxf(0.f, xx * sc[u] + sh[u]);
      acc[u] += w * xx;
    }
  };

  accum(v, dv);   // self loop (becomes dv^2 after final *dv)
  const int beg = roff[v], end = roff[v + 1];
  for (int base = beg; base < end; base += 64) {
    int cnt = min(64, end - base);
    int s = 0; float w = 0.f;
    if (lane < cnt) { s = csr[base + lane]; w = dinv[s]; }
    for (int j = 0; j < cnt; ++j) {
      int sj = __shfl(s, j, 64);
      float wj = __shfl(w, j, 64);
      accum(sj, wj);
    }
  }

  bf16* gv = g + (size_t)v * C + lane * VPL;
  if constexpr (VPL == 2) {
    bf16x2 o;
    o[0] = (bf16)(acc[0] * dv); o[1] = (bf16)(acc[1] * dv);
    *(bf16x2*)gv = o;
  } else {
    bf16x4 o;
#pragma unroll
    for (int u = 0; u < 4; ++u) o[u] = (bf16)(acc[u] * dv);
    *(bf16x4*)gv = o;
  }
}

// ---------------- BatchNorm ----------------
// sums/scale/shift are in STORED channel order; gamma/beta are source-order.
__global__ void k_bnfinal(const float* __restrict__ sums, const float* __restrict__ gamma,
                          const float* __restrict__ beta, float* __restrict__ scale,
                          float* __restrict__ shift, int C, float invN) {
  int c = blockIdx.x * 256 + threadIdx.x;
  if (c >= C) return;
  int src = perm_src(c);
  float mu = sums[c] * invN;
  float var = sums[C + c] * invN - mu * mu;   // biased var (ddof=0)
  float is = rsqrtf(var + 1e-5f);
  float sc = gamma[src] * is;
  scale[c] = sc;
  shift[c] = beta[src] - mu * sc;
}

// in-place BN+ReLU, 8-wide (pad rows processed too: finite garbage, masked downstream)
template<int C>
__global__ void k_bnapply(bf16* __restrict__ g, const float* __restrict__ scale,
                          const float* __restrict__ shift, size_t total) {
  size_t base = ((size_t)blockIdx.x * 256 + threadIdx.x) * 8;
  if (base >= total) return;
  int col = (int)(base & (size_t)(C - 1));
  bf16x8 t = *(const bf16x8*)(g + base);
  bf16x8 o;
#pragma unroll
  for (int j = 0; j < 8; ++j)
    o[j] = (bf16)fmaxf(0.f, (float)t[j] * scale[col + j] + shift[col + j]);
  *(bf16x8*)(g + base) = o;
}

// ---------------- launch ----------------
extern "C" void kernel_launch(void* const* d_in, const int* in_sizes, int n_in,
                              void* d_out, int out_size, void* d_ws, size_t ws_size,
                              hipStream_t stream) {
  const float* x   = (const float*)d_in[0];
  const int*   ei  = (const int*)d_in[1];
  const float* W1  = (const float*)d_in[2];
  // d_in[3] = b1: absorbed by BN (mean subtraction cancels it)
  const float* g1  = (const float*)d_in[4];
  const float* be1 = (const float*)d_in[5];
  const float* W2  = (const float*)d_in[6];
  // d_in[7] = b2: absorbed by BN
  const float* g2  = (const float*)d_in[8];
  const float* be2 = (const float*)d_in[9];
  const float* Wl  = (const float*)d_in[10];
  const float* bl  = (const float*)d_in[11];
  float* out = (float*)d_out;

  const int N  = in_sizes[0] / 128;          // 50000
  const int E  = in_sizes[1] / 2;            // 500000
  const int Mp = ((N + 127) / 128) * 128;    // 50048 = 391*128
  const int NB = (N + 255) / 256;            // scan blocks (196)

  char* p = (char*)d_ws;
  auto carve = [&](size_t bytes) { void* r = (void*)p; p += (bytes + 255) & ~(size_t)255; return r; };
  int*   deg   = (int*)carve(sizeof(int) * N);
  int*   cur   = (int*)carve(sizeof(int) * N);
  int*   roff  = (int*)carve(sizeof(int) * (N + 1));
  int*   csr   = (int*)carve(sizeof(int) * E);
  int*   bsum  = (int*)carve(sizeof(int) * 256);
  int*   bpre  = (int*)carve(sizeof(int) * 256);
  float* dinv  = (float*)carve(sizeof(float) * N);
  float* sums1 = (float*)carve(sizeof(float) * 512);
  float* sums2 = (float*)carve(sizeof(float) * 1024);
  float* sc1   = (float*)carve(sizeof(float) * 256);
  float* sh1   = (float*)carve(sizeof(float) * 256);
  float* sc2   = (float*)carve(sizeof(float) * 512);
  float* sh2   = (float*)carve(sizeof(float) * 512);
  bf16*  w1t   = (bf16*)carve(sizeof(bf16) * 256 * 128);
  bf16*  w2t   = (bf16*)carve(sizeof(bf16) * 512 * 256);
  bf16*  wlt   = (bf16*)carve(sizeof(bf16) * 128 * 512);
  bf16*  xb    = (bf16*)carve(sizeof(bf16) * (size_t)Mp * 128);
  bf16*  ax1   = (bf16*)carve(sizeof(bf16) * (size_t)Mp * 128);  // agg(x)
  bf16*  t1    = (bf16*)carve(sizeof(bf16) * (size_t)Mp * 256);  // ax1 @ W1 (stored order)
  bf16*  ax2   = (bf16*)carve(sizeof(bf16) * (size_t)Mp * 256);  // agg(relu(bn(t1)))
  bf16*  t2    = (bf16*)carve(sizeof(bf16) * (size_t)Mp * 512);  // ax2 @ W2 (stored order)
  (void)n_in; (void)out_size; (void)ws_size;

  const int gE = (E + 255) / 256;
  k_init<<<NB, 256, 0, stream>>>(deg, cur, sums1, sums2, N);
  k_count<<<gE, 256, 0, stream>>>(ei, deg, E);
  k_scan1<<<NB, 256, 0, stream>>>(deg, bsum, N);
  k_scan2<<<1, 256, 0, stream>>>(bsum, bpre, NB);
  k_scan3<<<NB, 256, 0, stream>>>(deg, bpre, roff, dinv, N);   // dinv fused
  k_scatter<<<gE, 256, 0, stream>>>(ei, roff, cur, csr, E);

  k_cvt_x<<<(int)(((size_t)N * 128 / 4 + 255) / 256), 256, 0, stream>>>(x, xb, (size_t)N * 128);
  k_cvt_w<<<896, 256, 0, stream>>>(W1, W2, Wl, w1t, w2t, wlt);

  const int gAgg = (N + 3) / 4;
  // layer 1: aggregate first (S commutes with dense transform), then GEMM(+stats)
  k_agg<128, false><<<gAgg, 256, 0, stream>>>(xb, ax1, csr, roff, dinv, nullptr, nullptr, N);
  k_gemm<128, 256, false><<<dim3(Mp / 128, 2), 256, 0, stream>>>(ax1, w1t, t1, nullptr, nullptr, sums1, N);
  k_bnfinal<<<1, 256, 0, stream>>>(sums1, g1, be1, sc1, sh1, 256, 1.f / (float)N);

  // layer 2: gather applies BN1+ReLU on the fly (stored-channel order throughout)
  k_agg<256, true><<<gAgg, 256, 0, stream>>>(t1, ax2, csr, roff, dinv, sc1, sh1, N);
  k_gemm<256, 512, false><<<dim3(Mp / 128, 4), 256, 0, stream>>>(ax2, w2t, t2, nullptr, nullptr, sums2, N);
  k_bnfinal<<<2, 256, 0, stream>>>(sums2, g2, be2, sc2, sh2, 512, 1.f / (float)N);
  k_bnapply<512><<<(int)(((size_t)Mp * 512 / 8 + 255) / 256), 256, 0, stream>>>(t2, sc2, sh2, (size_t)Mp * 512);

  // final linear: out = a2 @ Wl + bl (fp32 natural-layout store, masked to real rows)
  k_gemm<512, 128, true><<<dim3(Mp / 128, 1), 256, 0, stream>>>(t2, wlt, nullptr, out, bl, nullptr, N);
}

// Round 7
// 390.681 us; speedup vs baseline: 1.6665x; 1.5463x over previous
//
#include <hip/hip_runtime.h>
#include <cstdint>
#include <cstddef>

typedef __bf16 bf16;
typedef bf16 bf16x2 __attribute__((ext_vector_type(2)));
typedef bf16 bf16x4 __attribute__((ext_vector_type(4)));
typedef bf16 bf16x8 __attribute__((ext_vector_type(8)));
typedef float f32x4 __attribute__((ext_vector_type(4)));

// ---------------- graph preprocessing ----------------
__global__ void k_init(int* __restrict__ deg, int* __restrict__ cur,
                       float* __restrict__ sums1, float* __restrict__ sums2, int N) {
  int i = blockIdx.x * 256 + threadIdx.x;
  if (i < N) { deg[i] = 1; cur[i] = 0; }   // deg starts at 1: self loop
  if (i < 512)  sums1[i] = 0.f;
  if (i < 1024) sums2[i] = 0.f;
}

__global__ void k_count(const int* __restrict__ ei, int* __restrict__ deg, int E) {
  int e = blockIdx.x * 256 + threadIdx.x;
  if (e < E) atomicAdd(&deg[ei[E + e]], 1);   // dst = ei[E+e]
}

// hierarchical scan of (deg-1): scan1 block sums -> scan2 scans sums -> scan3 writes roff
__global__ __launch_bounds__(256) void k_scan1(const int* __restrict__ deg,
                                               int* __restrict__ bsum, int N) {
  int t = threadIdx.x;
  int i = blockIdx.x * 256 + t;
  int v = (i < N) ? deg[i] - 1 : 0;
#pragma unroll
  for (int off = 32; off > 0; off >>= 1) v += __shfl_down(v, off, 64);
  __shared__ int red[4];
  if ((t & 63) == 0) red[t >> 6] = v;
  __syncthreads();
  if (t == 0) bsum[blockIdx.x] = red[0] + red[1] + red[2] + red[3];
}

__global__ __launch_bounds__(256) void k_scan2(const int* __restrict__ bsum,
                                               int* __restrict__ bpre, int B) {
  __shared__ int s[256];
  int t = threadIdx.x;
  int v = (t < B) ? bsum[t] : 0;
  s[t] = v;
  __syncthreads();
  for (int off = 1; off < 256; off <<= 1) {
    int add = (t >= off) ? s[t - off] : 0;
    __syncthreads();
    s[t] += add;
    __syncthreads();
  }
  if (t < B) bpre[t] = s[t] - v;   // exclusive
}

__global__ __launch_bounds__(256) void k_scan3(const int* __restrict__ deg,
                                               const int* __restrict__ bpre,
                                               int* __restrict__ roff,
                                               float* __restrict__ dinv, int N) {
  __shared__ int s[256];
  int t = threadIdx.x;
  int i = blockIdx.x * 256 + t;
  int d = (i < N) ? deg[i] : 1;
  int v = d - 1;
  if (i >= N) v = 0;
  s[t] = v;
  __syncthreads();
  for (int off = 1; off < 256; off <<= 1) {
    int add = (t >= off) ? s[t - off] : 0;
    __syncthreads();
    s[t] += add;
    __syncthreads();
  }
  if (i < N) {
    int base = bpre[blockIdx.x];
    roff[i] = base + s[t] - v;
    dinv[i] = rsqrtf((float)d);
    if (i == N - 1) roff[N] = base + s[t];
  }
}

__global__ void k_scatter(const int* __restrict__ ei, const int* __restrict__ roff,
                          int* __restrict__ cur, int* __restrict__ csr, int E) {
  int e = blockIdx.x * 256 + threadIdx.x;
  if (e >= E) return;
  int d = ei[E + e];
  int p = atomicAdd(&cur[d], 1);
  csr[roff[d] + p] = ei[e];   // src
}

// ---------------- dtype conversion ----------------
__global__ void k_cvt_x(const float* __restrict__ x, bf16* __restrict__ xb, size_t total) {
  size_t base = ((size_t)blockIdx.x * 256 + threadIdx.x) * 4;
  if (base >= total) return;
  const float4 v = *(const float4*)(x + base);
  bf16x4 o;
  o[0] = (bf16)v.x; o[1] = (bf16)v.y; o[2] = (bf16)v.z; o[3] = (bf16)v.w;
  *(bf16x4*)(xb + base) = o;
}

// merged transpose+cast of all three weights: Wt[n][k] = W[k][n]
__global__ void k_cvt_w(const float* __restrict__ W1, const float* __restrict__ W2,
                        const float* __restrict__ Wl, bf16* __restrict__ w1t,
                        bf16* __restrict__ w2t, bf16* __restrict__ wlt) {
  int i = blockIdx.x * 256 + threadIdx.x;   // grid covers 229376 exactly
  if (i < 32768) {
    int n = i >> 7, k = i & 127;
    w1t[i] = (bf16)W1[(size_t)k * 256 + n];
  } else if (i < 163840) {
    int j = i - 32768;
    int n = j >> 8, k = j & 255;
    w2t[j] = (bf16)W2[(size_t)k * 512 + n];
  } else {
    int j = i - 163840;
    int n = j >> 9, k = j & 511;
    wlt[j] = (bf16)Wl[(size_t)k * 128 + n];
  }
}

// ---------------- bf16 MFMA GEMM: C[M,NOUT] = A[M,K] @ Bt[NOUT,K]^T ----------------
// R7 = R3 structure (LDS [kb][row] layout, identical frag reads + epilogue)
// with REGISTER-STAGED DOUBLE BUFFERING replacing global_load_lds:
//   - plain global_load_dwordx4 into VGPRs, 4 consecutive lanes = 4 contiguous
//     16B chunks of one row (one 64B line -> TA coalesces, 16 lines/instr,
//     4x fewer L2 requests than the lane-per-row global_load_lds pattern);
//   - tile k+1 loads issue BEFORE tile k is consumed; pending VGPR loads
//     need no drain at __syncthreads (no shared state), so HBM latency +
//     TA queue time overlap the MFMA+LDS phase (the R3 barrier drained
//     everything, serializing ~3.8K cyc/iter);
//   - ds_write_b128 of the regs (4-way write bank conflict, ~1.58x on 2
//     instrs/wave/iter: negligible).
template<int K, int NOUT, bool FINAL>
__global__ __launch_bounds__(256) void k_gemm(const bf16* __restrict__ A,
                                              const bf16* __restrict__ Bt,
                                              bf16* __restrict__ outB,
                                              float* __restrict__ outF,
                                              const float* __restrict__ bias,
                                              float* __restrict__ sums,
                                              int Mreal) {
  __shared__ uint4 lA[512];
  __shared__ uint4 lB[512];
  const int tid = threadIdx.x;
  const int wv = tid >> 6, lane = tid & 63;
  const int q = lane >> 4, mr = lane & 15;
  const int m0 = blockIdx.x * 128;
  const int n0 = blockIdx.y * 128;
  const int rw = (wv >> 1) * 64, cw = (wv & 1) * 64;

  // staging map: phase it in {0,1}: idx = it*256+tid; row = idx>>2, chunk j = idx&3
  const int r0 = tid >> 2, j0 = tid & 3;   // phase 1 row = r0 + 64, same j
  const bf16* gA0 = A + (size_t)(m0 + r0) * K + j0 * 8;
  const bf16* gA1 = A + (size_t)(m0 + 64 + r0) * K + j0 * 8;
  const bf16* gB0 = Bt + (size_t)(n0 + r0) * K + j0 * 8;
  const bf16* gB1 = Bt + (size_t)(n0 + 64 + r0) * K + j0 * 8;
  const int sl0 = j0 * 128 + r0;           // LDS slot: kb*128 + row (kb = j)
  const int sl1 = j0 * 128 + 64 + r0;

  f32x4 acc[4][4];
#pragma unroll
  for (int r = 0; r < 4; ++r)
#pragma unroll
    for (int c = 0; c < 4; ++c) acc[r][c] = (f32x4){0.f, 0.f, 0.f, 0.f};

  uint4 pA0 = *(const uint4*)(gA0);
  uint4 pA1 = *(const uint4*)(gA1);
  uint4 pB0 = *(const uint4*)(gB0);
  uint4 pB1 = *(const uint4*)(gB1);

  for (int k0 = 0; k0 < K; k0 += 32) {
    uint4 nA0 = pA0, nA1 = pA1, nB0 = pB0, nB1 = pB1;
    if (k0 + 32 < K) {           // prefetch next tile into registers (in flight
      nA0 = *(const uint4*)(gA0 + k0 + 32);   //  across the whole consume phase)
      nA1 = *(const uint4*)(gA1 + k0 + 32);
      nB0 = *(const uint4*)(gB0 + k0 + 32);
      nB1 = *(const uint4*)(gB1 + k0 + 32);
    }
    __syncthreads();             // all waves done reading previous tile
    lA[sl0] = pA0; lA[sl1] = pA1;
    lB[sl0] = pB0; lB[sl1] = pB1;
    __syncthreads();             // tile visible to all waves
    bf16x8 af[4], bfr[4];
#pragma unroll
    for (int r = 0; r < 4; ++r)
      af[r] = ((const bf16x8*)lA)[q * 128 + rw + r * 16 + mr];
#pragma unroll
    for (int c = 0; c < 4; ++c)
      bfr[c] = ((const bf16x8*)lB)[q * 128 + cw + c * 16 + mr];
#pragma unroll
    for (int r = 0; r < 4; ++r)
#pragma unroll
      for (int c = 0; c < 4; ++c)
        acc[r][c] = __builtin_amdgcn_mfma_f32_16x16x32_bf16(af[r], bfr[c], acc[r][c], 0, 0, 0);
    pA0 = nA0; pA1 = nA1; pB0 = nB0; pB1 = nB1;
  }

  // C/D layout: col = lane&15, row = (lane>>4)*4 + reg (m89/m91-verified)
#pragma unroll
  for (int c = 0; c < 4; ++c) {
    const int col = n0 + cw + c * 16 + mr;
    float s0 = 0.f, s1 = 0.f;
#pragma unroll
    for (int r = 0; r < 4; ++r) {
#pragma unroll
      for (int i = 0; i < 4; ++i) {
        int row = m0 + rw + r * 16 + q * 4 + i;
        float v = acc[r][c][i];
        if (FINAL) {
          if (row < Mreal) outF[(size_t)row * NOUT + col] = v + bias[col];
        } else {
          outB[(size_t)row * NOUT + col] = (bf16)v;
          if (row < Mreal) { s0 += v; s1 += v * v; }
        }
      }
    }
    if (!FINAL) {
      s0 += __shfl_xor(s0, 16, 64); s0 += __shfl_xor(s0, 32, 64);
      s1 += __shfl_xor(s1, 16, 64); s1 += __shfl_xor(s1, 32, 64);
      if (q == 0) { atomicAdd(&sums[col], s0); atomicAdd(&sums[NOUT + col], s1); }
    }
  }
}

// ---------------- CSR aggregation (one wave per node) ----------------
// g[v] = dinv[v] * ( sum_e dinv[s]*f(h[s]) + dinv[v]*f(h[v]) )
// f = identity or fused BN+ReLU of prev layer (per-channel scale/shift in regs).
template<int C, bool BN>
__global__ __launch_bounds__(256) void k_agg(const bf16* __restrict__ h,
                                             bf16* __restrict__ g,
                                             const int* __restrict__ csr,
                                             const int* __restrict__ roff,
                                             const float* __restrict__ dinv,
                                             const float* __restrict__ scale,
                                             const float* __restrict__ shift,
                                             int N) {
  constexpr int VPL = C / 64;   // channels per lane: 2 or 4
  const int lane = threadIdx.x & 63;
  const int v = (int)(((unsigned)blockIdx.x * 256 + threadIdx.x) >> 6);
  if (v >= N) return;
  float sc[VPL], sh[VPL];
  if constexpr (BN) {
#pragma unroll
    for (int u = 0; u < VPL; ++u) { sc[u] = scale[lane * VPL + u]; sh[u] = shift[lane * VPL + u]; }
  }
  const float dv = dinv[v];
  float acc[VPL];
#pragma unroll
  for (int u = 0; u < VPL; ++u) acc[u] = 0.f;

  auto accum = [&](int src, float w) {
    const bf16* hr = h + (size_t)src * C + lane * VPL;
    float vals[VPL];
    if constexpr (VPL == 2) {
      bf16x2 t = *(const bf16x2*)hr;
      vals[0] = (float)t[0]; vals[1] = (float)t[1];
    } else {
      bf16x4 t = *(const bf16x4*)hr;
#pragma unroll
      for (int u = 0; u < 4; ++u) vals[u] = (float)t[u];
    }
#pragma unroll
    for (int u = 0; u < VPL; ++u) {
      float xx = vals[u];
      if constexpr (BN) xx = fmaxf(0.f, xx * sc[u] + sh[u]);
      acc[u] += w * xx;
    }
  };

  accum(v, dv);   // self loop (becomes dv^2 after final *dv)
  const int beg = roff[v], end = roff[v + 1];
  for (int base = beg; base < end; base += 64) {
    int cnt = min(64, end - base);
    int s = 0; float w = 0.f;
    if (lane < cnt) { s = csr[base + lane]; w = dinv[s]; }
    for (int j = 0; j < cnt; ++j) {
      int sj = __shfl(s, j, 64);
      float wj = __shfl(w, j, 64);
      accum(sj, wj);
    }
  }

  bf16* gv = g + (size_t)v * C + lane * VPL;
  if constexpr (VPL == 2) {
    bf16x2 o;
    o[0] = (bf16)(acc[0] * dv); o[1] = (bf16)(acc[1] * dv);
    *(bf16x2*)gv = o;
  } else {
    bf16x4 o;
#pragma unroll
    for (int u = 0; u < 4; ++u) o[u] = (bf16)(acc[u] * dv);
    *(bf16x4*)gv = o;
  }
}

// ---------------- BatchNorm ----------------
__global__ void k_bnfinal(const float* __restrict__ sums, const float* __restrict__ gamma,
                          const float* __restrict__ beta, float* __restrict__ scale,
                          float* __restrict__ shift, int C, float invN) {
  int c = blockIdx.x * 256 + threadIdx.x;
  if (c >= C) return;
  float mu = sums[c] * invN;
  float var = sums[C + c] * invN - mu * mu;   // biased var (ddof=0)
  float is = rsqrtf(var + 1e-5f);
  float sc = gamma[c] * is;
  scale[c] = sc;
  shift[c] = beta[c] - mu * sc;
}

// in-place BN+ReLU, 8-wide (pad rows processed too: finite garbage, masked downstream)
template<int C>
__global__ void k_bnapply(bf16* __restrict__ g, const float* __restrict__ scale,
                          const float* __restrict__ shift, size_t total) {
  size_t base = ((size_t)blockIdx.x * 256 + threadIdx.x) * 8;
  if (base >= total) return;
  int col = (int)(base & (size_t)(C - 1));
  bf16x8 t = *(const bf16x8*)(g + base);
  bf16x8 o;
#pragma unroll
  for (int j = 0; j < 8; ++j)
    o[j] = (bf16)fmaxf(0.f, (float)t[j] * scale[col + j] + shift[col + j]);
  *(bf16x8*)(g + base) = o;
}

// ---------------- launch ----------------
extern "C" void kernel_launch(void* const* d_in, const int* in_sizes, int n_in,
                              void* d_out, int out_size, void* d_ws, size_t ws_size,
                              hipStream_t stream) {
  const float* x   = (const float*)d_in[0];
  const int*   ei  = (const int*)d_in[1];
  const float* W1  = (const float*)d_in[2];
  // d_in[3] = b1: absorbed by BN (mean subtraction cancels it)
  const float* g1  = (const float*)d_in[4];
  const float* be1 = (const float*)d_in[5];
  const float* W2  = (const float*)d_in[6];
  // d_in[7] = b2: absorbed by BN
  const float* g2  = (const float*)d_in[8];
  const float* be2 = (const float*)d_in[9];
  const float* Wl  = (const float*)d_in[10];
  const float* bl  = (const float*)d_in[11];
  float* out = (float*)d_out;

  const int N  = in_sizes[0] / 128;          // 50000
  const int E  = in_sizes[1] / 2;            // 500000
  const int Mp = ((N + 127) / 128) * 128;    // 50048 = 391*128
  const int NB = (N + 255) / 256;            // scan blocks (196)

  char* p = (char*)d_ws;
  auto carve = [&](size_t bytes) { void* r = (void*)p; p += (bytes + 255) & ~(size_t)255; return r; };
  int*   deg   = (int*)carve(sizeof(int) * N);
  int*   cur   = (int*)carve(sizeof(int) * N);
  int*   roff  = (int*)carve(sizeof(int) * (N + 1));
  int*   csr   = (int*)carve(sizeof(int) * E);
  int*   bsum  = (int*)carve(sizeof(int) * 256);
  int*   bpre  = (int*)carve(sizeof(int) * 256);
  float* dinv  = (float*)carve(sizeof(float) * N);
  float* sums1 = (float*)carve(sizeof(float) * 512);
  float* sums2 = (float*)carve(sizeof(float) * 1024);
  float* sc1   = (float*)carve(sizeof(float) * 256);
  float* sh1   = (float*)carve(sizeof(float) * 256);
  float* sc2   = (float*)carve(sizeof(float) * 512);
  float* sh2   = (float*)carve(sizeof(float) * 512);
  bf16*  w1t   = (bf16*)carve(sizeof(bf16) * 256 * 128);
  bf16*  w2t   = (bf16*)carve(sizeof(bf16) * 512 * 256);
  bf16*  wlt   = (bf16*)carve(sizeof(bf16) * 128 * 512);
  bf16*  xb    = (bf16*)carve(sizeof(bf16) * (size_t)Mp * 128);
  bf16*  ax1   = (bf16*)carve(sizeof(bf16) * (size_t)Mp * 128);  // agg(x)
  bf16*  t1    = (bf16*)carve(sizeof(bf16) * (size_t)Mp * 256);  // ax1 @ W1
  bf16*  ax2   = (bf16*)carve(sizeof(bf16) * (size_t)Mp * 256);  // agg(relu(bn(t1)))
  bf16*  t2    = (bf16*)carve(sizeof(bf16) * (size_t)Mp * 512);  // ax2 @ W2, then bn+relu in place
  (void)n_in; (void)out_size; (void)ws_size;

  const int gE = (E + 255) / 256;
  k_init<<<NB, 256, 0, stream>>>(deg, cur, sums1, sums2, N);
  k_count<<<gE, 256, 0, stream>>>(ei, deg, E);
  k_scan1<<<NB, 256, 0, stream>>>(deg, bsum, N);
  k_scan2<<<1, 256, 0, stream>>>(bsum, bpre, NB);
  k_scan3<<<NB, 256, 0, stream>>>(deg, bpre, roff, dinv, N);   // dinv fused
  k_scatter<<<gE, 256, 0, stream>>>(ei, roff, cur, csr, E);

  k_cvt_x<<<(int)(((size_t)N * 128 / 4 + 255) / 256), 256, 0, stream>>>(x, xb, (size_t)N * 128);
  k_cvt_w<<<896, 256, 0, stream>>>(W1, W2, Wl, w1t, w2t, wlt);

  const int gAgg = (N + 3) / 4;
  // layer 1: aggregate first (S commutes with dense transform), then GEMM(+stats)
  k_agg<128, false><<<gAgg, 256, 0, stream>>>(xb, ax1, csr, roff, dinv, nullptr, nullptr, N);
  k_gemm<128, 256, false><<<dim3(Mp / 128, 2), 256, 0, stream>>>(ax1, w1t, t1, nullptr, nullptr, sums1, N);
  k_bnfinal<<<1, 256, 0, stream>>>(sums1, g1, be1, sc1, sh1, 256, 1.f / (float)N);

  // layer 2: gather applies BN1+ReLU on the fly
  k_agg<256, true><<<gAgg, 256, 0, stream>>>(t1, ax2, csr, roff, dinv, sc1, sh1, N);
  k_gemm<256, 512, false><<<dim3(Mp / 128, 4), 256, 0, stream>>>(ax2, w2t, t2, nullptr, nullptr, sums2, N);
  k_bnfinal<<<2, 256, 0, stream>>>(sums2, g2, be2, sc2, sh2, 512, 1.f / (float)N);
  k_bnapply<512><<<(int)(((size_t)Mp * 512 / 8 + 255) / 256), 256, 0, stream>>>(t2, sc2, sh2, (size_t)Mp * 512);

  // final linear: out = a2 @ Wl + bl (fp32 store, masked to real rows)
  k_gemm<512, 128, true><<<dim3(Mp / 128, 1), 256, 0, stream>>>(t2, wlt, nullptr, out, bl, nullptr, N);
}

// Round 8
// 382.909 us; speedup vs baseline: 1.7004x; 1.0203x over previous
//
#include <hip/hip_runtime.h>
#include <cstdint>
#include <cstddef>

typedef __bf16 bf16;
typedef bf16 bf16x2 __attribute__((ext_vector_type(2)));
typedef bf16 bf16x4 __attribute__((ext_vector_type(4)));
typedef bf16 bf16x8 __attribute__((ext_vector_type(8)));
typedef float f32x4 __attribute__((ext_vector_type(4)));

// ---------------- graph preprocessing ----------------
__global__ void k_init(int* __restrict__ deg, int* __restrict__ cur,
                       float* __restrict__ sums1, float* __restrict__ sums2, int N) {
  int i = blockIdx.x * 256 + threadIdx.x;
  if (i < N) { deg[i] = 1; cur[i] = 0; }   // deg starts at 1: self loop
  if (i < 512)  sums1[i] = 0.f;
  if (i < 1024) sums2[i] = 0.f;
}

__global__ void k_count(const int* __restrict__ ei, int* __restrict__ deg, int E) {
  int e = blockIdx.x * 256 + threadIdx.x;
  if (e < E) atomicAdd(&deg[ei[E + e]], 1);   // dst = ei[E+e]
}

// hierarchical scan of (deg-1): scan1 block sums -> scan2 scans sums -> scan3 writes roff
__global__ __launch_bounds__(256) void k_scan1(const int* __restrict__ deg,
                                               int* __restrict__ bsum, int N) {
  int t = threadIdx.x;
  int i = blockIdx.x * 256 + t;
  int v = (i < N) ? deg[i] - 1 : 0;
#pragma unroll
  for (int off = 32; off > 0; off >>= 1) v += __shfl_down(v, off, 64);
  __shared__ int red[4];
  if ((t & 63) == 0) red[t >> 6] = v;
  __syncthreads();
  if (t == 0) bsum[blockIdx.x] = red[0] + red[1] + red[2] + red[3];
}

__global__ __launch_bounds__(256) void k_scan2(const int* __restrict__ bsum,
                                               int* __restrict__ bpre, int B) {
  __shared__ int s[256];
  int t = threadIdx.x;
  int v = (t < B) ? bsum[t] : 0;
  s[t] = v;
  __syncthreads();
  for (int off = 1; off < 256; off <<= 1) {
    int add = (t >= off) ? s[t - off] : 0;
    __syncthreads();
    s[t] += add;
    __syncthreads();
  }
  if (t < B) bpre[t] = s[t] - v;   // exclusive
}

__global__ __launch_bounds__(256) void k_scan3(const int* __restrict__ deg,
                                               const int* __restrict__ bpre,
                                               int* __restrict__ roff,
                                               float* __restrict__ dinv, int N) {
  __shared__ int s[256];
  int t = threadIdx.x;
  int i = blockIdx.x * 256 + t;
  int d = (i < N) ? deg[i] : 1;
  int v = d - 1;
  if (i >= N) v = 0;
  s[t] = v;
  __syncthreads();
  for (int off = 1; off < 256; off <<= 1) {
    int add = (t >= off) ? s[t - off] : 0;
    __syncthreads();
    s[t] += add;
    __syncthreads();
  }
  if (i < N) {
    int base = bpre[blockIdx.x];
    roff[i] = base + s[t] - v;
    dinv[i] = rsqrtf((float)d);
    if (i == N - 1) roff[N] = base + s[t];
  }
}

__global__ void k_scatter(const int* __restrict__ ei, const int* __restrict__ roff,
                          int* __restrict__ cur, int* __restrict__ csr, int E) {
  int e = blockIdx.x * 256 + threadIdx.x;
  if (e >= E) return;
  int d = ei[E + e];
  int p = atomicAdd(&cur[d], 1);
  csr[roff[d] + p] = ei[e];   // src
}

// ---------------- dtype conversion ----------------
__global__ void k_cvt_x(const float* __restrict__ x, bf16* __restrict__ xb, size_t total) {
  size_t base = ((size_t)blockIdx.x * 256 + threadIdx.x) * 4;
  if (base >= total) return;
  const float4 v = *(const float4*)(x + base);
  bf16x4 o;
  o[0] = (bf16)v.x; o[1] = (bf16)v.y; o[2] = (bf16)v.z; o[3] = (bf16)v.w;
  *(bf16x4*)(xb + base) = o;
}

// merged transpose+cast of all three weights: Wt[n][k] = W[k][n]
__global__ void k_cvt_w(const float* __restrict__ W1, const float* __restrict__ W2,
                        const float* __restrict__ Wl, bf16* __restrict__ w1t,
                        bf16* __restrict__ w2t, bf16* __restrict__ wlt) {
  int i = blockIdx.x * 256 + threadIdx.x;   // grid covers 229376 exactly
  if (i < 32768) {
    int n = i >> 7, k = i & 127;
    w1t[i] = (bf16)W1[(size_t)k * 256 + n];
  } else if (i < 163840) {
    int j = i - 32768;
    int n = j >> 8, k = j & 255;
    w2t[j] = (bf16)W2[(size_t)k * 512 + n];
  } else {
    int j = i - 163840;
    int n = j >> 9, k = j & 511;
    wlt[j] = (bf16)Wl[(size_t)k * 128 + n];
  }
}

// ---------------- bf16 MFMA GEMM: C[M,NOUT] = A[M,K] @ Bt[NOUT,K]^T ----------------
// R8 = R7 register-staged pipeline with three K-loop fixes:
//  (1) XOR row swizzle: slot(kb,row) = kb*ROWS + (row ^ (kb<<1)).
//      Writes: lane (r0,j) -> bank group (r0^2j)&7, uniform 8 lanes/group
//      (structural minimum). Reads: (mr^2q)&7, uniform. R7's [kb][row]
//      layout had 4-way write conflicts = 4.8M cycles (rocprof).
//  (2) LDS double-buffer, ONE __syncthreads per iter (write buf -> barrier
//      -> read buf; next iter uses buf^1, race-free since read(buf) always
//      precedes the next barrier).
//  (3) FINAL uses 64-row m-tiles: 782 blocks instead of 391 (which left
//      half the 256 CUs idle).
template<int K, int NOUT, bool FINAL>
__global__ __launch_bounds__(256) void k_gemm(const bf16* __restrict__ A,
                                              const bf16* __restrict__ Bt,
                                              bf16* __restrict__ outB,
                                              float* __restrict__ outF,
                                              const float* __restrict__ bias,
                                              float* __restrict__ sums,
                                              int Mreal) {
  constexpr int MT  = FINAL ? 64 : 128;   // m-tile rows
  constexpr int RPW = MT / 32;            // 16-row subtiles per wave (2 or 4)
  __shared__ uint4 lA[2][MT * 4];
  __shared__ uint4 lB[2][512];
  const int tid = threadIdx.x;
  const int wv = tid >> 6, lane = tid & 63;
  const int q = lane >> 4, mr = lane & 15;
  const int m0 = blockIdx.x * MT;
  const int n0 = blockIdx.y * 128;
  const int rw = (wv >> 1) * (MT / 2), cw = (wv & 1) * 64;

  // staging map: thread -> (row r0, k-chunk j0); 4 consecutive lanes = one 64B line
  const int r0 = tid >> 2, j0 = tid & 3;
  const bf16* gA0 = A + (size_t)(m0 + (MT == 64 ? r0 : r0)) * K + j0 * 8;
  const bf16* gA1 = A + (size_t)(m0 + 64 + r0) * K + j0 * 8;   // MT==128 only
  const bf16* gB0 = Bt + (size_t)(n0 + r0) * K + j0 * 8;
  const bf16* gB1 = Bt + (size_t)(n0 + 64 + r0) * K + j0 * 8;
  const int swz = j0 << 1;
  const int slA0 = j0 * MT + (r0 ^ swz);
  const int slA1 = j0 * MT + ((r0 + 64) ^ swz);                // MT==128 only
  const int slB0 = j0 * 128 + (r0 ^ swz);
  const int slB1 = j0 * 128 + ((r0 + 64) ^ swz);

  f32x4 acc[RPW][4];
#pragma unroll
  for (int r = 0; r < RPW; ++r)
#pragma unroll
    for (int c = 0; c < 4; ++c) acc[r][c] = (f32x4){0.f, 0.f, 0.f, 0.f};

  uint4 pA0 = *(const uint4*)(gA0);
  uint4 pA1, pB1;
  if constexpr (MT == 128) pA1 = *(const uint4*)(gA1);
  uint4 pB0 = *(const uint4*)(gB0);
  pB1 = *(const uint4*)(gB1);

  const int qs = q << 1;   // read-side XOR key
  int buf = 0;
  for (int k0 = 0; k0 < K; k0 += 32, buf ^= 1) {
    uint4 nA0 = pA0, nA1 = pA1, nB0 = pB0, nB1 = pB1;
    if (k0 + 32 < K) {     // prefetch next tile into registers
      nA0 = *(const uint4*)(gA0 + k0 + 32);
      if constexpr (MT == 128) nA1 = *(const uint4*)(gA1 + k0 + 32);
      nB0 = *(const uint4*)(gB0 + k0 + 32);
      nB1 = *(const uint4*)(gB1 + k0 + 32);
    }
    lA[buf][slA0] = pA0;
    if constexpr (MT == 128) lA[buf][slA1] = pA1;
    lB[buf][slB0] = pB0;
    lB[buf][slB1] = pB1;
    __syncthreads();       // single barrier: tile visible, prev buf free next iter
    bf16x8 af[RPW], bfr[4];
#pragma unroll
    for (int r = 0; r < RPW; ++r)
      af[r] = ((const bf16x8*)lA[buf])[q * MT + ((rw + r * 16 + mr) ^ qs)];
#pragma unroll
    for (int c = 0; c < 4; ++c)
      bfr[c] = ((const bf16x8*)lB[buf])[q * 128 + ((cw + c * 16 + mr) ^ qs)];
#pragma unroll
    for (int r = 0; r < RPW; ++r)
#pragma unroll
      for (int c = 0; c < 4; ++c)
        acc[r][c] = __builtin_amdgcn_mfma_f32_16x16x32_bf16(af[r], bfr[c], acc[r][c], 0, 0, 0);
    pA0 = nA0; pA1 = nA1; pB0 = nB0; pB1 = nB1;
  }

  // C/D layout: col = lane&15, row = (lane>>4)*4 + reg (m89/m91-verified)
#pragma unroll
  for (int c = 0; c < 4; ++c) {
    const int col = n0 + cw + c * 16 + mr;
    float s0 = 0.f, s1 = 0.f;
#pragma unroll
    for (int r = 0; r < RPW; ++r) {
#pragma unroll
      for (int i = 0; i < 4; ++i) {
        int row = m0 + rw + r * 16 + q * 4 + i;
        float v = acc[r][c][i];
        if (FINAL) {
          if (row < Mreal) outF[(size_t)row * NOUT + col] = v + bias[col];
        } else {
          outB[(size_t)row * NOUT + col] = (bf16)v;
          if (row < Mreal) { s0 += v; s1 += v * v; }
        }
      }
    }
    if (!FINAL) {
      s0 += __shfl_xor(s0, 16, 64); s0 += __shfl_xor(s0, 32, 64);
      s1 += __shfl_xor(s1, 16, 64); s1 += __shfl_xor(s1, 32, 64);
      if (q == 0) { atomicAdd(&sums[col], s0); atomicAdd(&sums[NOUT + col], s1); }
    }
  }
}

// ---------------- CSR aggregation (one wave per node) ----------------
// g[v] = dinv[v] * ( sum_e dinv[s]*f(h[s]) + dinv[v]*f(h[v]) )
// f = identity or fused BN+ReLU of prev layer (per-channel scale/shift in regs).
template<int C, bool BN>
__global__ __launch_bounds__(256) void k_agg(const bf16* __restrict__ h,
                                             bf16* __restrict__ g,
                                             const int* __restrict__ csr,
                                             const int* __restrict__ roff,
                                             const float* __restrict__ dinv,
                                             const float* __restrict__ scale,
                                             const float* __restrict__ shift,
                                             int N) {
  constexpr int VPL = C / 64;   // channels per lane: 2 or 4
  const int lane = threadIdx.x & 63;
  const int v = (int)(((unsigned)blockIdx.x * 256 + threadIdx.x) >> 6);
  if (v >= N) return;
  float sc[VPL], sh[VPL];
  if constexpr (BN) {
#pragma unroll
    for (int u = 0; u < VPL; ++u) { sc[u] = scale[lane * VPL + u]; sh[u] = shift[lane * VPL + u]; }
  }
  const float dv = dinv[v];
  float acc[VPL];
#pragma unroll
  for (int u = 0; u < VPL; ++u) acc[u] = 0.f;

  auto accum = [&](int src, float w) {
    const bf16* hr = h + (size_t)src * C + lane * VPL;
    float vals[VPL];
    if constexpr (VPL == 2) {
      bf16x2 t = *(const bf16x2*)hr;
      vals[0] = (float)t[0]; vals[1] = (float)t[1];
    } else {
      bf16x4 t = *(const bf16x4*)hr;
#pragma unroll
      for (int u = 0; u < 4; ++u) vals[u] = (float)t[u];
    }
#pragma unroll
    for (int u = 0; u < VPL; ++u) {
      float xx = vals[u];
      if constexpr (BN) xx = fmaxf(0.f, xx * sc[u] + sh[u]);
      acc[u] += w * xx;
    }
  };

  accum(v, dv);   // self loop (becomes dv^2 after final *dv)
  const int beg = roff[v], end = roff[v + 1];
  for (int base = beg; base < end; base += 64) {
    int cnt = min(64, end - base);
    int s = 0; float w = 0.f;
    if (lane < cnt) { s = csr[base + lane]; w = dinv[s]; }
    for (int j = 0; j < cnt; ++j) {
      int sj = __shfl(s, j, 64);
      float wj = __shfl(w, j, 64);
      accum(sj, wj);
    }
  }

  bf16* gv = g + (size_t)v * C + lane * VPL;
  if constexpr (VPL == 2) {
    bf16x2 o;
    o[0] = (bf16)(acc[0] * dv); o[1] = (bf16)(acc[1] * dv);
    *(bf16x2*)gv = o;
  } else {
    bf16x4 o;
#pragma unroll
    for (int u = 0; u < 4; ++u) o[u] = (bf16)(acc[u] * dv);
    *(bf16x4*)gv = o;
  }
}

// ---------------- BatchNorm ----------------
__global__ void k_bnfinal(const float* __restrict__ sums, const float* __restrict__ gamma,
                          const float* __restrict__ beta, float* __restrict__ scale,
                          float* __restrict__ shift, int C, float invN) {
  int c = blockIdx.x * 256 + threadIdx.x;
  if (c >= C) return;
  float mu = sums[c] * invN;
  float var = sums[C + c] * invN - mu * mu;   // biased var (ddof=0)
  float is = rsqrtf(var + 1e-5f);
  float sc = gamma[c] * is;
  scale[c] = sc;
  shift[c] = beta[c] - mu * sc;
}

// in-place BN+ReLU, 8-wide (pad rows processed too: finite garbage, masked downstream)
template<int C>
__global__ void k_bnapply(bf16* __restrict__ g, const float* __restrict__ scale,
                          const float* __restrict__ shift, size_t total) {
  size_t base = ((size_t)blockIdx.x * 256 + threadIdx.x) * 8;
  if (base >= total) return;
  int col = (int)(base & (size_t)(C - 1));
  bf16x8 t = *(const bf16x8*)(g + base);
  bf16x8 o;
#pragma unroll
  for (int j = 0; j < 8; ++j)
    o[j] = (bf16)fmaxf(0.f, (float)t[j] * scale[col + j] + shift[col + j]);
  *(bf16x8*)(g + base) = o;
}

// ---------------- launch ----------------
extern "C" void kernel_launch(void* const* d_in, const int* in_sizes, int n_in,
                              void* d_out, int out_size, void* d_ws, size_t ws_size,
                              hipStream_t stream) {
  const float* x   = (const float*)d_in[0];
  const int*   ei  = (const int*)d_in[1];
  const float* W1  = (const float*)d_in[2];
  // d_in[3] = b1: absorbed by BN (mean subtraction cancels it)
  const float* g1  = (const float*)d_in[4];
  const float* be1 = (const float*)d_in[5];
  const float* W2  = (const float*)d_in[6];
  // d_in[7] = b2: absorbed by BN
  const float* g2  = (const float*)d_in[8];
  const float* be2 = (const float*)d_in[9];
  const float* Wl  = (const float*)d_in[10];
  const float* bl  = (const float*)d_in[11];
  float* out = (float*)d_out;

  const int N  = in_sizes[0] / 128;          // 50000
  const int E  = in_sizes[1] / 2;            // 500000
  const int Mp = ((N + 127) / 128) * 128;    // 50048 = 391*128 = 782*64
  const int NB = (N + 255) / 256;            // scan blocks (196)

  char* p = (char*)d_ws;
  auto carve = [&](size_t bytes) { void* r = (void*)p; p += (bytes + 255) & ~(size_t)255; return r; };
  int*   deg   = (int*)carve(sizeof(int) * N);
  int*   cur   = (int*)carve(sizeof(int) * N);
  int*   roff  = (int*)carve(sizeof(int) * (N + 1));
  int*   csr   = (int*)carve(sizeof(int) * E);
  int*   bsum  = (int*)carve(sizeof(int) * 256);
  int*   bpre  = (int*)carve(sizeof(int) * 256);
  float* dinv  = (float*)carve(sizeof(float) * N);
  float* sums1 = (float*)carve(sizeof(float) * 512);
  float* sums2 = (float*)carve(sizeof(float) * 1024);
  float* sc1   = (float*)carve(sizeof(float) * 256);
  float* sh1   = (float*)carve(sizeof(float) * 256);
  float* sc2   = (float*)carve(sizeof(float) * 512);
  float* sh2   = (float*)carve(sizeof(float) * 512);
  bf16*  w1t   = (bf16*)carve(sizeof(bf16) * 256 * 128);
  bf16*  w2t   = (bf16*)carve(sizeof(bf16) * 512 * 256);
  bf16*  wlt   = (bf16*)carve(sizeof(bf16) * 128 * 512);
  bf16*  xb    = (bf16*)carve(sizeof(bf16) * (size_t)Mp * 128);
  bf16*  ax1   = (bf16*)carve(sizeof(bf16) * (size_t)Mp * 128);  // agg(x)
  bf16*  t1    = (bf16*)carve(sizeof(bf16) * (size_t)Mp * 256);  // ax1 @ W1
  bf16*  ax2   = (bf16*)carve(sizeof(bf16) * (size_t)Mp * 256);  // agg(relu(bn(t1)))
  bf16*  t2    = (bf16*)carve(sizeof(bf16) * (size_t)Mp * 512);  // ax2 @ W2, then bn+relu in place
  (void)n_in; (void)out_size; (void)ws_size;

  const int gE = (E + 255) / 256;
  k_init<<<NB, 256, 0, stream>>>(deg, cur, sums1, sums2, N);
  k_count<<<gE, 256, 0, stream>>>(ei, deg, E);
  k_scan1<<<NB, 256, 0, stream>>>(deg, bsum, N);
  k_scan2<<<1, 256, 0, stream>>>(bsum, bpre, NB);
  k_scan3<<<NB, 256, 0, stream>>>(deg, bpre, roff, dinv, N);   // dinv fused
  k_scatter<<<gE, 256, 0, stream>>>(ei, roff, cur, csr, E);

  k_cvt_x<<<(int)(((size_t)N * 128 / 4 + 255) / 256), 256, 0, stream>>>(x, xb, (size_t)N * 128);
  k_cvt_w<<<896, 256, 0, stream>>>(W1, W2, Wl, w1t, w2t, wlt);

  const int gAgg = (N + 3) / 4;
  // layer 1: aggregate first (S commutes with dense transform), then GEMM(+stats)
  k_agg<128, false><<<gAgg, 256, 0, stream>>>(xb, ax1, csr, roff, dinv, nullptr, nullptr, N);
  k_gemm<128, 256, false><<<dim3(Mp / 128, 2), 256, 0, stream>>>(ax1, w1t, t1, nullptr, nullptr, sums1, N);
  k_bnfinal<<<1, 256, 0, stream>>>(sums1, g1, be1, sc1, sh1, 256, 1.f / (float)N);

  // layer 2: gather applies BN1+ReLU on the fly
  k_agg<256, true><<<gAgg, 256, 0, stream>>>(t1, ax2, csr, roff, dinv, sc1, sh1, N);
  k_gemm<256, 512, false><<<dim3(Mp / 128, 4), 256, 0, stream>>>(ax2, w2t, t2, nullptr, nullptr, sums2, N);
  k_bnfinal<<<2, 256, 0, stream>>>(sums2, g2, be2, sc2, sh2, 512, 1.f / (float)N);
  k_bnapply<512><<<(int)(((size_t)Mp * 512 / 8 + 255) / 256), 256, 0, stream>>>(t2, sc2, sh2, (size_t)Mp * 512);

  // final linear: out = a2 @ Wl + bl (fp32 store, masked to real rows; 64-row tiles)
  k_gemm<512, 128, true><<<dim3(Mp / 64, 1), 256, 0, stream>>>(t2, wlt, nullptr, out, bl, nullptr, N);
}